// Round 12
// baseline (428.333 us; speedup 1.0000x reference)
//
#include <hip/hip_runtime.h>
#include <hip/hip_bf16.h>

#define MUL 32

typedef _Float16 f16x8 __attribute__((ext_vector_type(8)));
typedef float f32x4 __attribute__((ext_vector_type(4)));

static __device__ __forceinline__ float silu_f(float z) {
    return z / (1.0f + __expf(-z));
}

// ---------------------------------------------------------------------------
// Kernel A: per-node pre-pass. sc -> d_out (f32), y -> ws (f16). (r9-verified)
// ---------------------------------------------------------------------------
__global__ __launch_bounds__(128) void node_pre_kernel(
    const float* __restrict__ x, const float* __restrict__ attr,
    const float* __restrict__ Wsc0, const float* __restrict__ Wsc1,
    const float* __restrict__ Wl10, const float* __restrict__ Wl11,
    float* __restrict__ sc_out, _Float16* __restrict__ y_out, int N)
{
    __shared__ float sW[4][MUL * MUL];
    __shared__ float xs[128];
    const int tid = threadIdx.x;
    for (int i = tid; i < MUL * MUL; i += 128) {
        sW[0][i] = Wsc0[i];
        sW[1][i] = Wsc1[i];
        sW[2][i] = Wl10[i];
        sW[3][i] = Wl11[i];
    }
    __syncthreads();

    const float inv = 0.17677669529663687f; // 1/sqrt(32)
    for (int n = blockIdx.x; n < N; n += gridDim.x) {
        xs[tid] = x[(size_t)n * 128 + tid];
        __syncthreads();
        const float scale = inv * attr[n];
        if (tid < MUL) {
            float acc0 = 0.f, acc1 = 0.f;
#pragma unroll
            for (int u = 0; u < MUL; ++u) {
                const float xv = xs[u];
                acc0 += xv * sW[0][u * MUL + tid];
                acc1 += xv * sW[2][u * MUL + tid];
            }
            sc_out[(size_t)n * 128 + tid] = acc0 * scale;
            y_out [(size_t)n * 128 + tid] = (_Float16)(acc1 * scale);
        } else {
            const int idx = tid - MUL;
            const int v = idx / 3, c = idx - v * 3;
            float acc0 = 0.f, acc1 = 0.f;
#pragma unroll
            for (int u = 0; u < MUL; ++u) {
                const float xv = xs[MUL + u * 3 + c];
                acc0 += xv * sW[1][u * MUL + v];
                acc1 += xv * sW[3][u * MUL + v];
            }
            sc_out[(size_t)n * 128 + tid] = acc0 * scale;
            y_out [(size_t)n * 128 + tid] = (_Float16)(acc1 * scale);
        }
        __syncthreads();
    }
}

// ---------------------------------------------------------------------------
// CSR build: histogram -> scan -> fill. (unchanged, verified r4-r11)
// ---------------------------------------------------------------------------
__global__ void hist_kernel(const int* __restrict__ edst, int* __restrict__ deg, int E)
{
    int i = blockIdx.x * blockDim.x + threadIdx.x;
    const int stride = gridDim.x * blockDim.x;
    for (; i < E; i += stride) atomicAdd(&deg[edst[i]], 1);
}

__global__ __launch_bounds__(1024) void scan_kernel(
    const int* __restrict__ deg, int* __restrict__ row_ptr, int N, int E)
{
    __shared__ int part[1024];
    const int tid = threadIdx.x;
    const int chunk = (N + 1023) / 1024;
    const int lo = min(tid * chunk, N), hi = min(lo + chunk, N);
    int s = 0;
    for (int k = lo; k < hi; ++k) s += deg[k];
    part[tid] = s;
    __syncthreads();
    for (int off = 1; off < 1024; off <<= 1) {
        const int add = (tid >= off) ? part[tid - off] : 0;
        __syncthreads();
        part[tid] += add;
        __syncthreads();
    }
    int run = part[tid] - s;
    for (int k = lo; k < hi; ++k) {
        row_ptr[k] = run;
        run += deg[k];
    }
    if (hi == N) row_ptr[N] = E;
}

__global__ void fill_kernel(
    const int* __restrict__ esrc, const int* __restrict__ edst,
    const float* __restrict__ esh,
    const int* __restrict__ row_ptr, int* __restrict__ cur,
    int* __restrict__ csr2edge, int* __restrict__ src_s, float4* __restrict__ sh_s,
    int E)
{
    int i = blockIdx.x * blockDim.x + threadIdx.x;
    const int stride = gridDim.x * blockDim.x;
    for (; i < E; i += stride) {
        const int d = edst[i];
        const int p = row_ptr[d] + atomicAdd(&cur[d], 1);
        csr2edge[p] = i;
        src_s[p] = esrc[i];
        sh_s[p] = *(const float4*)&esh[(size_t)i * 4];
    }
}

// ---------------------------------------------------------------------------
// Kernel B: edge MLP -> w (f16, EDGE order => sequential streaming stores).
// (unchanged from r11)
// ---------------------------------------------------------------------------
__global__ __launch_bounds__(256) void edge_w_kernel(
    const float* __restrict__ escal,
    const float* __restrict__ Wfc1, const float* __restrict__ Wfc2,
    _Float16* __restrict__ w_s, int E)
{
    __shared__ _Float16 sW2T[128 * 128];   // 32 KB, [col][k] swizzled
    __shared__ _Float16 sH[4][16 * 128];   // 4 KB per wave (h, then w staging)

    const int tid = threadIdx.x;
    const int wid = tid >> 6;
    const int l   = tid & 63;
    const int c16 = l & 15;
    const int kq  = l >> 4;

    _Float16* Hw = sH[wid];

    {
        int* z2 = (int*)sW2T;
        for (int i = tid; i < 128 * 128 / 2; i += 256) z2[i] = 0;
    }
    __syncthreads();
    for (int i = tid; i < 100 * 128; i += 256) {
        const int k = i >> 7, col = i & 127;
        sW2T[col * 128 + (k ^ ((col & 7) << 3))] = (_Float16)Wfc2[i];
    }

    f16x8 bW1[7];
#pragma unroll
    for (int cb = 0; cb < 7; ++cb) {
        const int col = cb * 16 + c16;
#pragma unroll
        for (int j = 0; j < 8; ++j) {
            const int k = kq * 8 + j;
            bW1[cb][j] = (k < 10 && col < 100) ? (_Float16)Wfc1[k * 100 + col]
                                               : (_Float16)0.f;
        }
    }
#pragma unroll
    for (int r = 0; r < 4; ++r) {
        const int row = kq * 4 + r;
        const int col = 112 + c16;
        Hw[row * 128 + (col ^ ((row & 7) << 3))] = (_Float16)0.f;
    }
    __syncthreads();   // W2T visible to all waves; no barriers after this

    const float inv_s10 = 0.31622776601683794f; // 1/sqrt(10)

    const int gw = blockIdx.x * 4 + wid;
    const int nw = gridDim.x * 4;

    for (int base = gw * 16; base < E; base += nw * 16) {
        const int ge = base + c16;

        f16x8 a1;
#pragma unroll
        for (int j = 0; j < 8; ++j) {
            const int k = kq * 8 + j;
            a1[j] = (k < 10 && ge < E) ? (_Float16)escal[(size_t)ge * 10 + k]
                                       : (_Float16)0.f;
        }

#pragma unroll
        for (int cb = 0; cb < 7; ++cb) {
            f32x4 z = {0.f, 0.f, 0.f, 0.f};
            z = __builtin_amdgcn_mfma_f32_16x16x32_f16(a1, bW1[cb], z, 0, 0, 0);
#pragma unroll
            for (int r = 0; r < 4; ++r) {
                const int row = kq * 4 + r;
                const int col = cb * 16 + c16;
                const float h = silu_f(z[r] * inv_s10) * 0.1f;
                Hw[row * 128 + (col ^ ((row & 7) << 3))] = (_Float16)h;
            }
        }

        f32x4 acc0 = {0.f,0.f,0.f,0.f}, acc1 = {0.f,0.f,0.f,0.f};
        f32x4 acc2 = {0.f,0.f,0.f,0.f}, acc3 = {0.f,0.f,0.f,0.f};
        f32x4 acc4 = {0.f,0.f,0.f,0.f}, acc5 = {0.f,0.f,0.f,0.f};
        f32x4 acc6 = {0.f,0.f,0.f,0.f}, acc7 = {0.f,0.f,0.f,0.f};
#pragma unroll
        for (int kk = 0; kk < 4; ++kk) {
            const f16x8 a2 = *(const f16x8*)&Hw[c16 * 128 +
                                ((kk * 32 + kq * 8) ^ ((c16 & 7) << 3))];
#define BFRAG(CB) (*(const f16x8*)&sW2T[((CB) * 16 + c16) * 128 + \
                       ((kk * 32 + kq * 8) ^ ((c16 & 7) << 3))])
            acc0 = __builtin_amdgcn_mfma_f32_16x16x32_f16(a2, BFRAG(0), acc0, 0, 0, 0);
            acc1 = __builtin_amdgcn_mfma_f32_16x16x32_f16(a2, BFRAG(1), acc1, 0, 0, 0);
            acc2 = __builtin_amdgcn_mfma_f32_16x16x32_f16(a2, BFRAG(2), acc2, 0, 0, 0);
            acc3 = __builtin_amdgcn_mfma_f32_16x16x32_f16(a2, BFRAG(3), acc3, 0, 0, 0);
            acc4 = __builtin_amdgcn_mfma_f32_16x16x32_f16(a2, BFRAG(4), acc4, 0, 0, 0);
            acc5 = __builtin_amdgcn_mfma_f32_16x16x32_f16(a2, BFRAG(5), acc5, 0, 0, 0);
            acc6 = __builtin_amdgcn_mfma_f32_16x16x32_f16(a2, BFRAG(6), acc6, 0, 0, 0);
            acc7 = __builtin_amdgcn_mfma_f32_16x16x32_f16(a2, BFRAG(7), acc7, 0, 0, 0);
#undef BFRAG
        }

#define STAGE_CB(CB, ACC)                                                     \
        {                                                                     \
            _Pragma("unroll")                                                 \
            for (int r = 0; r < 4; ++r) {                                     \
                const int row = kq * 4 + r;                                   \
                const int col = (CB) * 16 + c16;                              \
                Hw[row * 128 + (col ^ ((row & 7) << 3))] = (_Float16)(ACC)[r];\
            }                                                                 \
        }
        STAGE_CB(0, acc0) STAGE_CB(1, acc1) STAGE_CB(2, acc2) STAGE_CB(3, acc3)
        STAGE_CB(4, acc4) STAGE_CB(5, acc5) STAGE_CB(6, acc6) STAGE_CB(7, acc7)
#undef STAGE_CB

#pragma unroll
        for (int i = 0; i < 4; ++i) {
            const int e = i * 4 + (l >> 4);
            const int colb = (l & 15) * 8;
            const f16x8 v = *(const f16x8*)&Hw[e * 128 +
                                (colb ^ ((e & 7) << 3))];
            if (base + e < E)
                *(f16x8*)&w_s[(size_t)(base + e) * 128 + colb] = v;
        }
    }
}

// ---------------------------------------------------------------------------
// Kernel C: gather + mean + fused post. Wave-per-node, batched metadata:
// per 64-edge batch, lane L coalesced-loads csr2edge/src_s once; the edge
// loop gets indices via __shfl (no memory dependence) and runs 4-deep ILP.
// ---------------------------------------------------------------------------
__global__ __launch_bounds__(256) void gather_post_kernel(
    const _Float16* __restrict__ w_s, const int* __restrict__ src_s,
    const int* __restrict__ csr2edge,
    const float4* __restrict__ sh_s, const int* __restrict__ row_ptr,
    const _Float16* __restrict__ y, const float* __restrict__ attr,
    const float* __restrict__ Wl20, const float* __restrict__ Wl21,
    const float* __restrict__ Walpha,
    float* __restrict__ out, int N)
{
    __shared__ float sW0[64 * 32];
    __shared__ float sW1[64 * 32];
    __shared__ float sWa[64];
    __shared__ float sMid[4][256];   // per-wave: [mid0(64) | midT(3x64)]

    const int tid = threadIdx.x;
    for (int i = tid; i < 64 * 32; i += 256) {
        sW0[i] = Wl20[i];
        sW1[i] = Wl21[i];
    }
    if (tid < 64) sWa[tid] = Walpha[tid];
    __syncthreads();   // only barrier; node loop is barrier-free

    const int wid = tid >> 6;
    const int L   = tid & 63;
    const bool hi = (L >= 32);
    const int u   = L & 31;

    const int wAi = hi ? 32 + u : u;
    const int wBi = hi ? 96 + u : 64 + u;
    const int yi0 = hi ? 32 + 3 * u + 0 : u;
    const int yi1 = hi ? 32 + 3 * u + 1 : u;
    const int yi2 = hi ? 32 + 3 * u + 2 : u;
    const float mulA = hi ? 0.5773502691896258f : 1.0f;   // 1/sqrt(3) on m11

    const int o1m = L - 32;
    const int v1 = hi ? o1m / 3 : 0;
    const int c1 = hi ? o1m - v1 * 3 : 0;
    const int o2m = L + 32;
    const int v2 = o2m / 3;
    const int c2 = o2m - v2 * 3;
    const float* wcol1 = hi ? (sW1 + v1) : (sW0 + L);
    const float* wcol2 = sW1 + v2;

    float* midw = &sMid[wid][0];
    const float* msrc1c = hi ? (midw + 64 + c1 * 64) : midw;
    const float* msrc2c = midw + 64 + c2 * 64;

#define ACC_EDGE(sh, wAv, wBv, q0, q1, q2) do {                        \
        const float sA0 = hi ? (sh).y : (sh).x;                        \
        const float sA1 = hi ? (sh).z : 0.f;                           \
        const float sA2 = hi ? (sh).w : 0.f;                           \
        const float b1s = hi ? (sh).x : (sh).y;                        \
        const float b2s = hi ? (sh).x : (sh).z;                        \
        const float b3s = hi ? (sh).x : (sh).w;                        \
        accA += (wAv) * mulA * ((q0) * sA0 + (q1) * sA1 + (q2) * sA2); \
        acc1 += (wBv) * (q0) * b1s;                                    \
        acc2 += (wBv) * (q1) * b2s;                                    \
        acc3 += (wBv) * (q2) * b3s;                                    \
    } while (0)

    const int waves_glob = gridDim.x * 4;
    for (int n = blockIdx.x * 4 + wid; n < N; n += waves_glob) {
        const int jlo = row_ptr[n];
        const int jhi = row_ptr[n + 1];
        const int deg = jhi - jlo;
        if (deg <= 0) continue;

        float accA = 0.f, acc1 = 0.f, acc2 = 0.f, acc3 = 0.f;

        for (int k0 = 0; k0 < deg; k0 += 64) {
            // batched metadata: one coalesced load per 64 edges
            int eL = 0, sL = 0;
            const int jme = jlo + k0 + L;
            if (jme < jhi) {
                eL = csr2edge[jme];
                sL = src_s[jme];
            }
            const int kmax = min(64, deg - k0);
            const int jb = jlo + k0;

            int k = 0;
            for (; k + 4 <= kmax; k += 4) {
                int e4[4], s4[4];
#pragma unroll
                for (int t = 0; t < 4; ++t) {
                    e4[t] = __shfl(eL, k + t);
                    s4[t] = __shfl(sL, k + t);
                }
                float4 sh4[4];
#pragma unroll
                for (int t = 0; t < 4; ++t) sh4[t] = sh_s[jb + k + t];
                float wA4[4], wB4[4], q04[4], q14[4], q24[4];
#pragma unroll
                for (int t = 0; t < 4; ++t) {
                    const _Float16* wr = w_s + (size_t)e4[t] * 128;
                    const _Float16* yr = y + (size_t)s4[t] * 128;
                    wA4[t] = (float)wr[wAi];
                    wB4[t] = (float)wr[wBi];
                    q04[t] = (float)yr[yi0];
                    q14[t] = (float)yr[yi1];
                    q24[t] = (float)yr[yi2];
                }
#pragma unroll
                for (int t = 0; t < 4; ++t)
                    ACC_EDGE(sh4[t], wA4[t], wB4[t], q04[t], q14[t], q24[t]);
            }
            for (; k < kmax; ++k) {
                const int ea = __shfl(eL, k);
                const int sa = __shfl(sL, k);
                const float4 shA = sh_s[jb + k];
                const _Float16* wra = w_s + (size_t)ea * 128;
                const _Float16* yra = y + (size_t)sa * 128;
                const float wAa = (float)wra[wAi], wBa = (float)wra[wBi];
                const float qa0 = (float)yra[yi0], qa1 = (float)yra[yi1],
                            qa2 = (float)yra[yi2];
                ACC_EDGE(shA, wAa, wBa, qa0, qa1, qa2);
            }
        }

        const float rdeg = 1.0f / (float)deg;
        const float a = attr[n];

        float term = accA * rdeg * sWa[L];
#pragma unroll
        for (int off = 32; off; off >>= 1) term += __shfl_xor(term, off);
        const float alpha = term * 0.125f * a;

        midw[L]            = accA * rdeg;
        midw[64 + L]       = acc1 * rdeg;
        midw[128 + L]      = acc2 * rdeg;
        midw[192 + L]      = acc3 * rdeg;

        float cv1 = 0.f, cv2 = 0.f;
#pragma unroll
        for (int kk = 0; kk < 16; ++kk) {
            const float4 m1 = *(const float4*)&msrc1c[4 * kk];
            const float4 m2 = *(const float4*)&msrc2c[4 * kk];
            cv1 += m1.x * wcol1[(4 * kk + 0) * 32] + m1.y * wcol1[(4 * kk + 1) * 32]
                 + m1.z * wcol1[(4 * kk + 2) * 32] + m1.w * wcol1[(4 * kk + 3) * 32];
            cv2 += m2.x * wcol2[(4 * kk + 0) * 32] + m2.y * wcol2[(4 * kk + 1) * 32]
                 + m2.z * wcol2[(4 * kk + 2) * 32] + m2.w * wcol2[(4 * kk + 3) * 32];
        }
        const float f = alpha * 0.125f * a;
        const size_t ob = (size_t)n * 128;
        out[ob + L]      += f * cv1;
        out[ob + 64 + L] += f * cv2;
    }
#undef ACC_EDGE
}

extern "C" void kernel_launch(void* const* d_in, const int* in_sizes, int n_in,
                              void* d_out, int out_size, void* d_ws, size_t ws_size,
                              hipStream_t stream)
{
    const float* x      = (const float*)d_in[0];
    const float* attr   = (const float*)d_in[1];
    const int*   esrc   = (const int*)  d_in[2];
    const int*   edst   = (const int*)  d_in[3];
    const float* esh    = (const float*)d_in[4];
    const float* escal  = (const float*)d_in[5];
    const float* Wfc1   = (const float*)d_in[6];
    const float* Wfc2   = (const float*)d_in[7];
    const float* Wsc0   = (const float*)d_in[8];
    const float* Wsc1   = (const float*)d_in[9];
    const float* Wl10   = (const float*)d_in[10];
    const float* Wl11   = (const float*)d_in[11];
    const float* Wl20   = (const float*)d_in[12];
    const float* Wl21   = (const float*)d_in[13];
    const float* Walpha = (const float*)d_in[14];

    const int N = in_sizes[1];
    const int E = in_sizes[2];
    float* out = (float*)d_out;

    // ws: y(f16) | row_ptr | deg | cur | csr2edge | src_s | [align16] sh_s | w_s
    char* p = (char*)d_ws;
    _Float16* y   = (_Float16*)p; p += (size_t)N * 128 * sizeof(_Float16);
    int* row_ptr  = (int*)p;      p += (size_t)(N + 1) * sizeof(int);
    int* deg      = (int*)p;      p += (size_t)N * sizeof(int);
    int* cur      = (int*)p;      p += (size_t)N * sizeof(int);
    int* csr2edge = (int*)p;      p += (size_t)E * sizeof(int);
    int* src_s    = (int*)p;      p += (size_t)E * sizeof(int);
    p = (char*)(((uintptr_t)p + 15) & ~(uintptr_t)15);
    float4* sh_s  = (float4*)p;   p += (size_t)E * sizeof(float4);
    _Float16* w_s = (_Float16*)p;

    hipMemsetAsync(deg, 0, (size_t)2 * N * sizeof(int), stream);

    node_pre_kernel<<<2048, 128, 0, stream>>>(x, attr, Wsc0, Wsc1, Wl10, Wl11,
                                              out, y, N);
    hist_kernel<<<512, 256, 0, stream>>>(edst, deg, E);
    scan_kernel<<<1, 1024, 0, stream>>>(deg, row_ptr, N, E);
    fill_kernel<<<512, 256, 0, stream>>>(esrc, edst, esh, row_ptr, cur,
                                         csr2edge, src_s, sh_s, E);
    edge_w_kernel<<<1024, 256, 0, stream>>>(escal, Wfc1, Wfc2, w_s, E);
    gather_post_kernel<<<4096, 256, 0, stream>>>(w_s, src_s, csr2edge, sh_s,
                                                 row_ptr, y, attr, Wl20, Wl21,
                                                 Walpha, out, N);
}

// Round 14
// 316.040 us; speedup vs baseline: 1.3553x; 1.3553x over previous
//
#include <hip/hip_runtime.h>
#include <hip/hip_bf16.h>

#define MUL 32

typedef _Float16 f16x8 __attribute__((ext_vector_type(8)));
typedef float f32x4 __attribute__((ext_vector_type(4)));

static __device__ __forceinline__ float silu_f(float z) {
    return z / (1.0f + __expf(-z));
}

// ---------------------------------------------------------------------------
// Kernel A: per-node pre-pass, wave-per-node, barrier-free.
//  Weights in VGPRs (128 regs), x row in wave-private LDS, branch-free
//  dual-output per lane: o1 = L, o2 = L + 64.
// ---------------------------------------------------------------------------
__global__ __launch_bounds__(256) void node_pre_kernel(
    const float* __restrict__ x, const float* __restrict__ attr,
    const float* __restrict__ Wsc0, const float* __restrict__ Wsc1,
    const float* __restrict__ Wl10, const float* __restrict__ Wl11,
    float* __restrict__ sc_out, _Float16* __restrict__ y_out, int N)
{
    __shared__ float sX[4][128];
    const int tid = threadIdx.x;
    const int wid = tid >> 6, L = tid & 63;
    float* xs = sX[wid];
    const float inv = 0.17677669529663687f; // 1/sqrt(32)

    // o1 = L: type0 (l0) if L<32 else type1 (l1, idx=L-32)
    const bool t0 = (L < 32);
    const int i1 = t0 ? 0 : (L - 32);
    const int v1 = i1 / 3, c1 = i1 - v1 * 3;
    // o2 = L+64: always type1, idx = L+32
    const int i2 = L + 32;
    const int v2 = i2 / 3, c2 = i2 - v2 * 3;

    const int xb1 = t0 ? 0 : (32 + c1);   // xs base for o1
    const int xst1 = t0 ? 1 : 3;          // xs stride for o1

    // hoist weights into registers (statically indexed -> stays in VGPRs)
    float wA[32], wB[32], wC[32], wD[32];
#pragma unroll
    for (int u = 0; u < 32; ++u) {
        wA[u] = t0 ? Wsc0[u * 32 + L] : Wsc1[u * 32 + v1];
        wB[u] = t0 ? Wl10[u * 32 + L] : Wl11[u * 32 + v1];
        wC[u] = Wsc1[u * 32 + v2];
        wD[u] = Wl11[u * 32 + v2];
    }

    const int stride = gridDim.x * 4;
    for (int n = blockIdx.x * 4 + wid; n < N; n += stride) {
        xs[L]      = x[(size_t)n * 128 + L];
        xs[64 + L] = x[(size_t)n * 128 + 64 + L];
        const float scale = inv * attr[n];
        float a0 = 0.f, a1 = 0.f, b0 = 0.f, b1 = 0.f;
#pragma unroll
        for (int u = 0; u < 32; ++u) {
            const float xv1 = xs[xb1 + u * xst1];
            const float xv2 = xs[32 + u * 3 + c2];
            a0 += xv1 * wA[u];
            a1 += xv1 * wB[u];
            b0 += xv2 * wC[u];
            b1 += xv2 * wD[u];
        }
        sc_out[(size_t)n * 128 + L]      = a0 * scale;
        sc_out[(size_t)n * 128 + 64 + L] = b0 * scale;
        y_out [(size_t)n * 128 + L]      = (_Float16)(a1 * scale);
        y_out [(size_t)n * 128 + 64 + L] = (_Float16)(b1 * scale);
    }
}

// ---------------------------------------------------------------------------
// CSR build: histogram -> scan -> fill. (unchanged, verified r4-r12)
// ---------------------------------------------------------------------------
__global__ void hist_kernel(const int* __restrict__ edst, int* __restrict__ deg, int E)
{
    int i = blockIdx.x * blockDim.x + threadIdx.x;
    const int stride = gridDim.x * blockDim.x;
    for (; i < E; i += stride) atomicAdd(&deg[edst[i]], 1);
}

__global__ __launch_bounds__(1024) void scan_kernel(
    const int* __restrict__ deg, int* __restrict__ row_ptr, int N, int E)
{
    __shared__ int part[1024];
    const int tid = threadIdx.x;
    const int chunk = (N + 1023) / 1024;
    const int lo = min(tid * chunk, N), hi = min(lo + chunk, N);
    int s = 0;
    for (int k = lo; k < hi; ++k) s += deg[k];
    part[tid] = s;
    __syncthreads();
    for (int off = 1; off < 1024; off <<= 1) {
        const int add = (tid >= off) ? part[tid - off] : 0;
        __syncthreads();
        part[tid] += add;
        __syncthreads();
    }
    int run = part[tid] - s;
    for (int k = lo; k < hi; ++k) {
        row_ptr[k] = run;
        run += deg[k];
    }
    if (hi == N) row_ptr[N] = E;
}

__global__ void fill_kernel(
    const int* __restrict__ esrc, const int* __restrict__ edst,
    const float* __restrict__ esh,
    const int* __restrict__ row_ptr, int* __restrict__ cur,
    int* __restrict__ csr2edge, int* __restrict__ src_s, float4* __restrict__ sh_s,
    int E)
{
    int i = blockIdx.x * blockDim.x + threadIdx.x;
    const int stride = gridDim.x * blockDim.x;
    for (; i < E; i += stride) {
        const int d = edst[i];
        const int p = row_ptr[d] + atomicAdd(&cur[d], 1);
        csr2edge[p] = i;
        src_s[p] = esrc[i];
        sh_s[p] = *(const float4*)&esh[(size_t)i * 4];
    }
}

// ---------------------------------------------------------------------------
// Kernel B: edge MLP -> w (f16, EDGE order, streaming stores) + 2-deep escal
// prefetch: next iteration's A1 loads issue right after phase 1 consumes the
// current fragment, hiding HBM latency under phase 2's MFMAs.
// ---------------------------------------------------------------------------
__global__ __launch_bounds__(256) void edge_w_kernel(
    const float* __restrict__ escal,
    const float* __restrict__ Wfc1, const float* __restrict__ Wfc2,
    _Float16* __restrict__ w_s, int E)
{
    __shared__ _Float16 sW2T[128 * 128];   // 32 KB, [col][k] swizzled
    __shared__ _Float16 sH[4][16 * 128];   // 4 KB per wave (h, then w staging)

    const int tid = threadIdx.x;
    const int wid = tid >> 6;
    const int l   = tid & 63;
    const int c16 = l & 15;
    const int kq  = l >> 4;

    _Float16* Hw = sH[wid];

    {
        int* z2 = (int*)sW2T;
        for (int i = tid; i < 128 * 128 / 2; i += 256) z2[i] = 0;
    }
    __syncthreads();
    for (int i = tid; i < 100 * 128; i += 256) {
        const int k = i >> 7, col = i & 127;
        sW2T[col * 128 + (k ^ ((col & 7) << 3))] = (_Float16)Wfc2[i];
    }

    f16x8 bW1[7];
#pragma unroll
    for (int cb = 0; cb < 7; ++cb) {
        const int col = cb * 16 + c16;
#pragma unroll
        for (int j = 0; j < 8; ++j) {
            const int k = kq * 8 + j;
            bW1[cb][j] = (k < 10 && col < 100) ? (_Float16)Wfc1[k * 100 + col]
                                               : (_Float16)0.f;
        }
    }
#pragma unroll
    for (int r = 0; r < 4; ++r) {
        const int row = kq * 4 + r;
        const int col = 112 + c16;
        Hw[row * 128 + (col ^ ((row & 7) << 3))] = (_Float16)0.f;
    }
    __syncthreads();   // W2T visible to all waves; no barriers after this

    const float inv_s10 = 0.31622776601683794f; // 1/sqrt(10)

    const int gw = blockIdx.x * 4 + wid;
    const int nw = gridDim.x * 4;
    const int step = nw * 16;

    // prologue: load A1 for first iteration
    int base = gw * 16;
    f16x8 a1;
    {
        const int ge = base + c16;
#pragma unroll
        for (int j = 0; j < 8; ++j) {
            const int k = kq * 8 + j;
            a1[j] = (k < 10 && ge < E) ? (_Float16)escal[(size_t)ge * 10 + k]
                                       : (_Float16)0.f;
        }
    }

    for (; base < E; base += step) {
        // ---- phase 1: h = silu(escal@W1/sqrt10)*0.1 -> Hw (swizzled) ----
#pragma unroll
        for (int cb = 0; cb < 7; ++cb) {
            f32x4 z = {0.f, 0.f, 0.f, 0.f};
            z = __builtin_amdgcn_mfma_f32_16x16x32_f16(a1, bW1[cb], z, 0, 0, 0);
#pragma unroll
            for (int r = 0; r < 4; ++r) {
                const int row = kq * 4 + r;
                const int col = cb * 16 + c16;
                const float h = silu_f(z[r] * inv_s10) * 0.1f;
                Hw[row * 128 + (col ^ ((row & 7) << 3))] = (_Float16)h;
            }
        }

        // ---- prefetch next iteration's A1 (overlaps phase 2) ----
        f16x8 a1n;
        {
            const int ge = base + step + c16;
#pragma unroll
            for (int j = 0; j < 8; ++j) {
                const int k = kq * 8 + j;
                a1n[j] = (k < 10 && ge < E)
                         ? (_Float16)escal[(size_t)ge * 10 + k]
                         : (_Float16)0.f;
            }
        }

        // ---- phase 2: w = H @ W2 (A from Hw, B from sW2T; 32 MFMA) ----
        f32x4 acc0 = {0.f,0.f,0.f,0.f}, acc1 = {0.f,0.f,0.f,0.f};
        f32x4 acc2 = {0.f,0.f,0.f,0.f}, acc3 = {0.f,0.f,0.f,0.f};
        f32x4 acc4 = {0.f,0.f,0.f,0.f}, acc5 = {0.f,0.f,0.f,0.f};
        f32x4 acc6 = {0.f,0.f,0.f,0.f}, acc7 = {0.f,0.f,0.f,0.f};
#pragma unroll
        for (int kk = 0; kk < 4; ++kk) {
            const f16x8 a2 = *(const f16x8*)&Hw[c16 * 128 +
                                ((kk * 32 + kq * 8) ^ ((c16 & 7) << 3))];
#define BFRAG(CB) (*(const f16x8*)&sW2T[((CB) * 16 + c16) * 128 + \
                       ((kk * 32 + kq * 8) ^ ((c16 & 7) << 3))])
            acc0 = __builtin_amdgcn_mfma_f32_16x16x32_f16(a2, BFRAG(0), acc0, 0, 0, 0);
            acc1 = __builtin_amdgcn_mfma_f32_16x16x32_f16(a2, BFRAG(1), acc1, 0, 0, 0);
            acc2 = __builtin_amdgcn_mfma_f32_16x16x32_f16(a2, BFRAG(2), acc2, 0, 0, 0);
            acc3 = __builtin_amdgcn_mfma_f32_16x16x32_f16(a2, BFRAG(3), acc3, 0, 0, 0);
            acc4 = __builtin_amdgcn_mfma_f32_16x16x32_f16(a2, BFRAG(4), acc4, 0, 0, 0);
            acc5 = __builtin_amdgcn_mfma_f32_16x16x32_f16(a2, BFRAG(5), acc5, 0, 0, 0);
            acc6 = __builtin_amdgcn_mfma_f32_16x16x32_f16(a2, BFRAG(6), acc6, 0, 0, 0);
            acc7 = __builtin_amdgcn_mfma_f32_16x16x32_f16(a2, BFRAG(7), acc7, 0, 0, 0);
#undef BFRAG
        }

        // ---- stage w into Hw (h is dead now; per-wave in-order LDS) ----
#define STAGE_CB(CB, ACC)                                                     \
        {                                                                     \
            _Pragma("unroll")                                                 \
            for (int r = 0; r < 4; ++r) {                                     \
                const int row = kq * 4 + r;                                   \
                const int col = (CB) * 16 + c16;                              \
                Hw[row * 128 + (col ^ ((row & 7) << 3))] = (_Float16)(ACC)[r];\
            }                                                                 \
        }
        STAGE_CB(0, acc0) STAGE_CB(1, acc1) STAGE_CB(2, acc2) STAGE_CB(3, acc3)
        STAGE_CB(4, acc4) STAGE_CB(5, acc5) STAGE_CB(6, acc6) STAGE_CB(7, acc7)
#undef STAGE_CB

        // ---- 4x coalesced f16x8 stores per lane (4KB contiguous / wave) ----
#pragma unroll
        for (int i = 0; i < 4; ++i) {
            const int e = i * 4 + (l >> 4);
            const int colb = (l & 15) * 8;
            const f16x8 v = *(const f16x8*)&Hw[e * 128 +
                                (colb ^ ((e & 7) << 3))];
            if (base + e < E)
                *(f16x8*)&w_s[(size_t)(base + e) * 128 + colb] = v;
        }

        a1 = a1n;
    }
}

// ---------------------------------------------------------------------------
// Kernel C: gather + mean + fused post. EXACT r11 version (95 us verified).
// ---------------------------------------------------------------------------
__global__ __launch_bounds__(256) void gather_post_kernel(
    const _Float16* __restrict__ w_s, const int* __restrict__ src_s,
    const int* __restrict__ csr2edge,
    const float4* __restrict__ sh_s, const int* __restrict__ row_ptr,
    const _Float16* __restrict__ y, const float* __restrict__ attr,
    const float* __restrict__ Wl20, const float* __restrict__ Wl21,
    const float* __restrict__ Walpha,
    float* __restrict__ out, int N)
{
    __shared__ float sW0[64 * 32];
    __shared__ float sW1[64 * 32];
    __shared__ float sWa[64];
    __shared__ float sMid[4][256];   // per-wave: [mid0(64) | midT(3x64)]

    const int tid = threadIdx.x;
    for (int i = tid; i < 64 * 32; i += 256) {
        sW0[i] = Wl20[i];
        sW1[i] = Wl21[i];
    }
    if (tid < 64) sWa[tid] = Walpha[tid];
    __syncthreads();   // only barrier; node loop is barrier-free

    const int wid = tid >> 6;
    const int L   = tid & 63;
    const bool hi = (L >= 32);
    const int u   = L & 31;

    const int wAi = hi ? 32 + u : u;
    const int wBi = hi ? 96 + u : 64 + u;
    const int yi0 = hi ? 32 + 3 * u + 0 : u;
    const int yi1 = hi ? 32 + 3 * u + 1 : u;
    const int yi2 = hi ? 32 + 3 * u + 2 : u;
    const float mulA = hi ? 0.5773502691896258f : 1.0f;   // 1/sqrt(3) on m11

    const int o1m = L - 32;
    const int v1 = hi ? o1m / 3 : 0;
    const int c1 = hi ? o1m - v1 * 3 : 0;
    const int o2m = L + 32;
    const int v2 = o2m / 3;
    const int c2 = o2m - v2 * 3;
    const float* wcol1 = hi ? (sW1 + v1) : (sW0 + L);
    const float* wcol2 = sW1 + v2;

    float* midw = &sMid[wid][0];
    const float* msrc1c = hi ? (midw + 64 + c1 * 64) : midw;
    const float* msrc2c = midw + 64 + c2 * 64;

#define ACC_EDGE(sh, wAv, wBv, q0, q1, q2) do {                        \
        const float sA0 = hi ? (sh).y : (sh).x;                        \
        const float sA1 = hi ? (sh).z : 0.f;                           \
        const float sA2 = hi ? (sh).w : 0.f;                           \
        const float b1s = hi ? (sh).x : (sh).y;                        \
        const float b2s = hi ? (sh).x : (sh).z;                        \
        const float b3s = hi ? (sh).x : (sh).w;                        \
        accA += (wAv) * mulA * ((q0) * sA0 + (q1) * sA1 + (q2) * sA2); \
        acc1 += (wBv) * (q0) * b1s;                                    \
        acc2 += (wBv) * (q1) * b2s;                                    \
        acc3 += (wBv) * (q2) * b3s;                                    \
    } while (0)

    const int waves_glob = gridDim.x * 4;
    for (int n = blockIdx.x * 4 + wid; n < N; n += waves_glob) {
        const int jlo = row_ptr[n];
        const int jhi = row_ptr[n + 1];
        const int deg = jhi - jlo;
        if (deg <= 0) continue;

        float accA = 0.f, acc1 = 0.f, acc2 = 0.f, acc3 = 0.f;

        int j = jlo;
        for (; j + 2 <= jhi; j += 2) {
            const int sa = src_s[j];
            const int sb = src_s[j + 1];
            const int ea = csr2edge[j];
            const int eb = csr2edge[j + 1];
            const float4 shA = sh_s[j];
            const float4 shB = sh_s[j + 1];
            const _Float16* wra = w_s + (size_t)ea * 128;
            const _Float16* wrb = w_s + (size_t)eb * 128;
            const _Float16* yra = y + (size_t)sa * 128;
            const _Float16* yrb = y + (size_t)sb * 128;
            const float wAa = (float)wra[wAi], wBa = (float)wra[wBi];
            const float qa0 = (float)yra[yi0], qa1 = (float)yra[yi1], qa2 = (float)yra[yi2];
            const float wAb = (float)wrb[wAi], wBb = (float)wrb[wBi];
            const float qb0 = (float)yrb[yi0], qb1 = (float)yrb[yi1], qb2 = (float)yrb[yi2];
            ACC_EDGE(shA, wAa, wBa, qa0, qa1, qa2);
            ACC_EDGE(shB, wAb, wBb, qb0, qb1, qb2);
        }
        if (j < jhi) {
            const int sa = src_s[j];
            const int ea = csr2edge[j];
            const float4 shA = sh_s[j];
            const _Float16* wra = w_s + (size_t)ea * 128;
            const _Float16* yra = y + (size_t)sa * 128;
            const float wAa = (float)wra[wAi], wBa = (float)wra[wBi];
            const float qa0 = (float)yra[yi0], qa1 = (float)yra[yi1], qa2 = (float)yra[yi2];
            ACC_EDGE(shA, wAa, wBa, qa0, qa1, qa2);
        }

        const float rdeg = 1.0f / (float)deg;
        const float a = attr[n];

        float term = accA * rdeg * sWa[L];
#pragma unroll
        for (int off = 32; off; off >>= 1) term += __shfl_xor(term, off);
        const float alpha = term * 0.125f * a;

        midw[L]            = accA * rdeg;
        midw[64 + L]       = acc1 * rdeg;
        midw[128 + L]      = acc2 * rdeg;
        midw[192 + L]      = acc3 * rdeg;

        float cv1 = 0.f, cv2 = 0.f;
#pragma unroll
        for (int kk = 0; kk < 16; ++kk) {
            const float4 m1 = *(const float4*)&msrc1c[4 * kk];
            const float4 m2 = *(const float4*)&msrc2c[4 * kk];
            cv1 += m1.x * wcol1[(4 * kk + 0) * 32] + m1.y * wcol1[(4 * kk + 1) * 32]
                 + m1.z * wcol1[(4 * kk + 2) * 32] + m1.w * wcol1[(4 * kk + 3) * 32];
            cv2 += m2.x * wcol2[(4 * kk + 0) * 32] + m2.y * wcol2[(4 * kk + 1) * 32]
                 + m2.z * wcol2[(4 * kk + 2) * 32] + m2.w * wcol2[(4 * kk + 3) * 32];
        }
        const float f = alpha * 0.125f * a;
        const size_t ob = (size_t)n * 128;
        out[ob + L]      += f * cv1;
        out[ob + 64 + L] += f * cv2;
    }
#undef ACC_EDGE
}

extern "C" void kernel_launch(void* const* d_in, const int* in_sizes, int n_in,
                              void* d_out, int out_size, void* d_ws, size_t ws_size,
                              hipStream_t stream)
{
    const float* x      = (const float*)d_in[0];
    const float* attr   = (const float*)d_in[1];
    const int*   esrc   = (const int*)  d_in[2];
    const int*   edst   = (const int*)  d_in[3];
    const float* esh    = (const float*)d_in[4];
    const float* escal  = (const float*)d_in[5];
    const float* Wfc1   = (const float*)d_in[6];
    const float* Wfc2   = (const float*)d_in[7];
    const float* Wsc0   = (const float*)d_in[8];
    const float* Wsc1   = (const float*)d_in[9];
    const float* Wl10   = (const float*)d_in[10];
    const float* Wl11   = (const float*)d_in[11];
    const float* Wl20   = (const float*)d_in[12];
    const float* Wl21   = (const float*)d_in[13];
    const float* Walpha = (const float*)d_in[14];

    const int N = in_sizes[1];
    const int E = in_sizes[2];
    float* out = (float*)d_out;

    // ws: y(f16) | row_ptr | deg | cur | csr2edge | src_s | [align16] sh_s | w_s
    char* p = (char*)d_ws;
    _Float16* y   = (_Float16*)p; p += (size_t)N * 128 * sizeof(_Float16);
    int* row_ptr  = (int*)p;      p += (size_t)(N + 1) * sizeof(int);
    int* deg      = (int*)p;      p += (size_t)N * sizeof(int);
    int* cur      = (int*)p;      p += (size_t)N * sizeof(int);
    int* csr2edge = (int*)p;      p += (size_t)E * sizeof(int);
    int* src_s    = (int*)p;      p += (size_t)E * sizeof(int);
    p = (char*)(((uintptr_t)p + 15) & ~(uintptr_t)15);
    float4* sh_s  = (float4*)p;   p += (size_t)E * sizeof(float4);
    _Float16* w_s = (_Float16*)p;

    hipMemsetAsync(deg, 0, (size_t)2 * N * sizeof(int), stream);

    node_pre_kernel<<<1024, 256, 0, stream>>>(x, attr, Wsc0, Wsc1, Wl10, Wl11,
                                              out, y, N);
    hist_kernel<<<512, 256, 0, stream>>>(edst, deg, E);
    scan_kernel<<<1, 1024, 0, stream>>>(deg, row_ptr, N, E);
    fill_kernel<<<512, 256, 0, stream>>>(esrc, edst, esh, row_ptr, cur,
                                         csr2edge, src_s, sh_s, E);
    edge_w_kernel<<<1024, 256, 0, stream>>>(escal, Wfc1, Wfc2, w_s, E);
    gather_post_kernel<<<4096, 256, 0, stream>>>(w_s, src_s, csr2edge, sh_s,
                                                 row_ptr, y, attr, Wl20, Wl21,
                                                 Walpha, out, N);
}

// Round 15
// 313.790 us; speedup vs baseline: 1.3650x; 1.0072x over previous
//
#include <hip/hip_runtime.h>
#include <hip/hip_bf16.h>

#define MUL 32

typedef _Float16 f16x8 __attribute__((ext_vector_type(8)));
typedef float f32x4 __attribute__((ext_vector_type(4)));

static __device__ __forceinline__ float silu_f(float z) {
    return z / (1.0f + __expf(-z));
}

// ---------------------------------------------------------------------------
// Kernel A: per-node pre-pass, wave-per-node, barrier-free. (r14-verified)
// ---------------------------------------------------------------------------
__global__ __launch_bounds__(256) void node_pre_kernel(
    const float* __restrict__ x, const float* __restrict__ attr,
    const float* __restrict__ Wsc0, const float* __restrict__ Wsc1,
    const float* __restrict__ Wl10, const float* __restrict__ Wl11,
    float* __restrict__ sc_out, _Float16* __restrict__ y_out, int N)
{
    __shared__ float sX[4][128];
    const int tid = threadIdx.x;
    const int wid = tid >> 6, L = tid & 63;
    float* xs = sX[wid];
    const float inv = 0.17677669529663687f; // 1/sqrt(32)

    const bool t0 = (L < 32);
    const int i1 = t0 ? 0 : (L - 32);
    const int v1 = i1 / 3, c1 = i1 - v1 * 3;
    const int i2 = L + 32;
    const int v2 = i2 / 3, c2 = i2 - v2 * 3;

    const int xb1 = t0 ? 0 : (32 + c1);
    const int xst1 = t0 ? 1 : 3;

    float wA[32], wB[32], wC[32], wD[32];
#pragma unroll
    for (int u = 0; u < 32; ++u) {
        wA[u] = t0 ? Wsc0[u * 32 + L] : Wsc1[u * 32 + v1];
        wB[u] = t0 ? Wl10[u * 32 + L] : Wl11[u * 32 + v1];
        wC[u] = Wsc1[u * 32 + v2];
        wD[u] = Wl11[u * 32 + v2];
    }

    const int stride = gridDim.x * 4;
    for (int n = blockIdx.x * 4 + wid; n < N; n += stride) {
        xs[L]      = x[(size_t)n * 128 + L];
        xs[64 + L] = x[(size_t)n * 128 + 64 + L];
        const float scale = inv * attr[n];
        float a0 = 0.f, a1 = 0.f, b0 = 0.f, b1 = 0.f;
#pragma unroll
        for (int u = 0; u < 32; ++u) {
            const float xv1 = xs[xb1 + u * xst1];
            const float xv2 = xs[32 + u * 3 + c2];
            a0 += xv1 * wA[u];
            a1 += xv1 * wB[u];
            b0 += xv2 * wC[u];
            b1 += xv2 * wD[u];
        }
        sc_out[(size_t)n * 128 + L]      = a0 * scale;
        sc_out[(size_t)n * 128 + 64 + L] = b0 * scale;
        y_out [(size_t)n * 128 + L]      = (_Float16)(a1 * scale);
        y_out [(size_t)n * 128 + 64 + L] = (_Float16)(b1 * scale);
    }
}

// ---------------------------------------------------------------------------
// CSR build: histogram -> scan -> fill. (unchanged, verified r4-r14)
// ---------------------------------------------------------------------------
__global__ void hist_kernel(const int* __restrict__ edst, int* __restrict__ deg, int E)
{
    int i = blockIdx.x * blockDim.x + threadIdx.x;
    const int stride = gridDim.x * blockDim.x;
    for (; i < E; i += stride) atomicAdd(&deg[edst[i]], 1);
}

__global__ __launch_bounds__(1024) void scan_kernel(
    const int* __restrict__ deg, int* __restrict__ row_ptr, int N, int E)
{
    __shared__ int part[1024];
    const int tid = threadIdx.x;
    const int chunk = (N + 1023) / 1024;
    const int lo = min(tid * chunk, N), hi = min(lo + chunk, N);
    int s = 0;
    for (int k = lo; k < hi; ++k) s += deg[k];
    part[tid] = s;
    __syncthreads();
    for (int off = 1; off < 1024; off <<= 1) {
        const int add = (tid >= off) ? part[tid - off] : 0;
        __syncthreads();
        part[tid] += add;
        __syncthreads();
    }
    int run = part[tid] - s;
    for (int k = lo; k < hi; ++k) {
        row_ptr[k] = run;
        run += deg[k];
    }
    if (hi == N) row_ptr[N] = E;
}

__global__ void fill_kernel(
    const int* __restrict__ esrc, const int* __restrict__ edst,
    const float* __restrict__ esh,
    const int* __restrict__ row_ptr, int* __restrict__ cur,
    int* __restrict__ csr2edge, int* __restrict__ src_s, float4* __restrict__ sh_s,
    int E)
{
    int i = blockIdx.x * blockDim.x + threadIdx.x;
    const int stride = gridDim.x * blockDim.x;
    for (; i < E; i += stride) {
        const int d = edst[i];
        const int p = row_ptr[d] + atomicAdd(&cur[d], 1);
        csr2edge[p] = i;
        src_s[p] = esrc[i];
        sh_s[p] = *(const float4*)&esh[(size_t)i * 4];
    }
}

// ---------------------------------------------------------------------------
// Kernel B: edge MLP -> w (f16, CSR-slot order => SEQUENTIAL streaming
// stores). The permutation is paid on the READ side: escal is gathered via
// csr2edge (scattered 40B reads, hidden under MFMA by 2-deep prefetch).
// ---------------------------------------------------------------------------
__global__ __launch_bounds__(256) void edge_w_kernel(
    const float* __restrict__ escal, const int* __restrict__ csr2edge,
    const float* __restrict__ Wfc1, const float* __restrict__ Wfc2,
    _Float16* __restrict__ w_s, int E)
{
    __shared__ _Float16 sW2T[128 * 128];   // 32 KB, [col][k] swizzled
    __shared__ _Float16 sH[4][16 * 128];   // 4 KB per wave (h, then w staging)

    const int tid = threadIdx.x;
    const int wid = tid >> 6;
    const int l   = tid & 63;
    const int c16 = l & 15;
    const int kq  = l >> 4;

    _Float16* Hw = sH[wid];

    {
        int* z2 = (int*)sW2T;
        for (int i = tid; i < 128 * 128 / 2; i += 256) z2[i] = 0;
    }
    __syncthreads();
    for (int i = tid; i < 100 * 128; i += 256) {
        const int k = i >> 7, col = i & 127;
        sW2T[col * 128 + (k ^ ((col & 7) << 3))] = (_Float16)Wfc2[i];
    }

    f16x8 bW1[7];
#pragma unroll
    for (int cb = 0; cb < 7; ++cb) {
        const int col = cb * 16 + c16;
#pragma unroll
        for (int j = 0; j < 8; ++j) {
            const int k = kq * 8 + j;
            bW1[cb][j] = (k < 10 && col < 100) ? (_Float16)Wfc1[k * 100 + col]
                                               : (_Float16)0.f;
        }
    }
#pragma unroll
    for (int r = 0; r < 4; ++r) {
        const int row = kq * 4 + r;
        const int col = 112 + c16;
        Hw[row * 128 + (col ^ ((row & 7) << 3))] = (_Float16)0.f;
    }
    __syncthreads();   // W2T visible to all waves; no barriers after this

    const float inv_s10 = 0.31622776601683794f; // 1/sqrt(10)

    const int gw = blockIdx.x * 4 + wid;
    const int nw = gridDim.x * 4;
    const int step = nw * 16;

    // prologue: csr2edge + gathered A1 for first iteration
    int base = gw * 16;
    f16x8 a1;
    {
        const int ge = base + c16;
        const int ee = (ge < E) ? csr2edge[ge] : 0;
#pragma unroll
        for (int j = 0; j < 8; ++j) {
            const int k = kq * 8 + j;
            a1[j] = (k < 10 && ge < E) ? (_Float16)escal[(size_t)ee * 10 + k]
                                       : (_Float16)0.f;
        }
    }

    for (; base < E; base += step) {
        // ---- phase 1: h = silu(escal@W1/sqrt10)*0.1 -> Hw (swizzled) ----
#pragma unroll
        for (int cb = 0; cb < 7; ++cb) {
            f32x4 z = {0.f, 0.f, 0.f, 0.f};
            z = __builtin_amdgcn_mfma_f32_16x16x32_f16(a1, bW1[cb], z, 0, 0, 0);
#pragma unroll
            for (int r = 0; r < 4; ++r) {
                const int row = kq * 4 + r;
                const int col = cb * 16 + c16;
                const float h = silu_f(z[r] * inv_s10) * 0.1f;
                Hw[row * 128 + (col ^ ((row & 7) << 3))] = (_Float16)h;
            }
        }

        // ---- prefetch next iteration's csr2edge + A1 (overlaps phase 2) ----
        f16x8 a1n;
        {
            const int ge = base + step + c16;
            const int ee = (ge < E) ? csr2edge[ge] : 0;
#pragma unroll
            for (int j = 0; j < 8; ++j) {
                const int k = kq * 8 + j;
                a1n[j] = (k < 10 && ge < E)
                         ? (_Float16)escal[(size_t)ee * 10 + k]
                         : (_Float16)0.f;
            }
        }

        // ---- phase 2: w = H @ W2 (A from Hw, B from sW2T; 32 MFMA) ----
        f32x4 acc0 = {0.f,0.f,0.f,0.f}, acc1 = {0.f,0.f,0.f,0.f};
        f32x4 acc2 = {0.f,0.f,0.f,0.f}, acc3 = {0.f,0.f,0.f,0.f};
        f32x4 acc4 = {0.f,0.f,0.f,0.f}, acc5 = {0.f,0.f,0.f,0.f};
        f32x4 acc6 = {0.f,0.f,0.f,0.f}, acc7 = {0.f,0.f,0.f,0.f};
#pragma unroll
        for (int kk = 0; kk < 4; ++kk) {
            const f16x8 a2 = *(const f16x8*)&Hw[c16 * 128 +
                                ((kk * 32 + kq * 8) ^ ((c16 & 7) << 3))];
#define BFRAG(CB) (*(const f16x8*)&sW2T[((CB) * 16 + c16) * 128 + \
                       ((kk * 32 + kq * 8) ^ ((c16 & 7) << 3))])
            acc0 = __builtin_amdgcn_mfma_f32_16x16x32_f16(a2, BFRAG(0), acc0, 0, 0, 0);
            acc1 = __builtin_amdgcn_mfma_f32_16x16x32_f16(a2, BFRAG(1), acc1, 0, 0, 0);
            acc2 = __builtin_amdgcn_mfma_f32_16x16x32_f16(a2, BFRAG(2), acc2, 0, 0, 0);
            acc3 = __builtin_amdgcn_mfma_f32_16x16x32_f16(a2, BFRAG(3), acc3, 0, 0, 0);
            acc4 = __builtin_amdgcn_mfma_f32_16x16x32_f16(a2, BFRAG(4), acc4, 0, 0, 0);
            acc5 = __builtin_amdgcn_mfma_f32_16x16x32_f16(a2, BFRAG(5), acc5, 0, 0, 0);
            acc6 = __builtin_amdgcn_mfma_f32_16x16x32_f16(a2, BFRAG(6), acc6, 0, 0, 0);
            acc7 = __builtin_amdgcn_mfma_f32_16x16x32_f16(a2, BFRAG(7), acc7, 0, 0, 0);
#undef BFRAG
        }

        // ---- stage w into Hw (h is dead now; per-wave in-order LDS) ----
#define STAGE_CB(CB, ACC)                                                     \
        {                                                                     \
            _Pragma("unroll")                                                 \
            for (int r = 0; r < 4; ++r) {                                     \
                const int row = kq * 4 + r;                                   \
                const int col = (CB) * 16 + c16;                              \
                Hw[row * 128 + (col ^ ((row & 7) << 3))] = (_Float16)(ACC)[r];\
            }                                                                 \
        }
        STAGE_CB(0, acc0) STAGE_CB(1, acc1) STAGE_CB(2, acc2) STAGE_CB(3, acc3)
        STAGE_CB(4, acc4) STAGE_CB(5, acc5) STAGE_CB(6, acc6) STAGE_CB(7, acc7)
#undef STAGE_CB

        // ---- 4x coalesced f16x8 stores per lane; CSR slots are consecutive
        //      => 4KB contiguous per wave per iteration ----
#pragma unroll
        for (int i = 0; i < 4; ++i) {
            const int e = i * 4 + (l >> 4);
            const int colb = (l & 15) * 8;
            const f16x8 v = *(const f16x8*)&Hw[e * 128 +
                                (colb ^ ((e & 7) << 3))];
            if (base + e < E)
                *(f16x8*)&w_s[(size_t)(base + e) * 128 + colb] = v;
        }

        a1 = a1n;
    }
}

// ---------------------------------------------------------------------------
// Kernel C: gather + mean + fused post. w_s now CSR-ordered => SEQUENTIAL
// w reads (no csr2edge). Only y[src] remains scattered (12.8MB, L2-resident).
// ---------------------------------------------------------------------------
__global__ __launch_bounds__(256) void gather_post_kernel(
    const _Float16* __restrict__ w_s, const int* __restrict__ src_s,
    const float4* __restrict__ sh_s, const int* __restrict__ row_ptr,
    const _Float16* __restrict__ y, const float* __restrict__ attr,
    const float* __restrict__ Wl20, const float* __restrict__ Wl21,
    const float* __restrict__ Walpha,
    float* __restrict__ out, int N)
{
    __shared__ float sW0[64 * 32];
    __shared__ float sW1[64 * 32];
    __shared__ float sWa[64];
    __shared__ float sMid[4][256];   // per-wave: [mid0(64) | midT(3x64)]

    const int tid = threadIdx.x;
    for (int i = tid; i < 64 * 32; i += 256) {
        sW0[i] = Wl20[i];
        sW1[i] = Wl21[i];
    }
    if (tid < 64) sWa[tid] = Walpha[tid];
    __syncthreads();   // only barrier; node loop is barrier-free

    const int wid = tid >> 6;
    const int L   = tid & 63;
    const bool hi = (L >= 32);
    const int u   = L & 31;

    const int wAi = hi ? 32 + u : u;
    const int wBi = hi ? 96 + u : 64 + u;
    const int yi0 = hi ? 32 + 3 * u + 0 : u;
    const int yi1 = hi ? 32 + 3 * u + 1 : u;
    const int yi2 = hi ? 32 + 3 * u + 2 : u;
    const float mulA = hi ? 0.5773502691896258f : 1.0f;   // 1/sqrt(3) on m11

    const int o1m = L - 32;
    const int v1 = hi ? o1m / 3 : 0;
    const int c1 = hi ? o1m - v1 * 3 : 0;
    const int o2m = L + 32;
    const int v2 = o2m / 3;
    const int c2 = o2m - v2 * 3;
    const float* wcol1 = hi ? (sW1 + v1) : (sW0 + L);
    const float* wcol2 = sW1 + v2;

    float* midw = &sMid[wid][0];
    const float* msrc1c = hi ? (midw + 64 + c1 * 64) : midw;
    const float* msrc2c = midw + 64 + c2 * 64;

#define ACC_EDGE(sh, wAv, wBv, q0, q1, q2) do {                        \
        const float sA0 = hi ? (sh).y : (sh).x;                        \
        const float sA1 = hi ? (sh).z : 0.f;                           \
        const float sA2 = hi ? (sh).w : 0.f;                           \
        const float b1s = hi ? (sh).x : (sh).y;                        \
        const float b2s = hi ? (sh).x : (sh).z;                        \
        const float b3s = hi ? (sh).x : (sh).w;                        \
        accA += (wAv) * mulA * ((q0) * sA0 + (q1) * sA1 + (q2) * sA2); \
        acc1 += (wBv) * (q0) * b1s;                                    \
        acc2 += (wBv) * (q1) * b2s;                                    \
        acc3 += (wBv) * (q2) * b3s;                                    \
    } while (0)

    const int waves_glob = gridDim.x * 4;
    for (int n = blockIdx.x * 4 + wid; n < N; n += waves_glob) {
        const int jlo = row_ptr[n];
        const int jhi = row_ptr[n + 1];
        const int deg = jhi - jlo;
        if (deg <= 0) continue;

        float accA = 0.f, acc1 = 0.f, acc2 = 0.f, acc3 = 0.f;

        int j = jlo;
        for (; j + 2 <= jhi; j += 2) {
            const int sa = src_s[j];
            const int sb = src_s[j + 1];
            const float4 shA = sh_s[j];
            const float4 shB = sh_s[j + 1];
            const _Float16* wra = w_s + (size_t)j * 128;
            const _Float16* wrb = wra + 128;
            const _Float16* yra = y + (size_t)sa * 128;
            const _Float16* yrb = y + (size_t)sb * 128;
            const float wAa = (float)wra[wAi], wBa = (float)wra[wBi];
            const float qa0 = (float)yra[yi0], qa1 = (float)yra[yi1], qa2 = (float)yra[yi2];
            const float wAb = (float)wrb[wAi], wBb = (float)wrb[wBi];
            const float qb0 = (float)yrb[yi0], qb1 = (float)yrb[yi1], qb2 = (float)yrb[yi2];
            ACC_EDGE(shA, wAa, wBa, qa0, qa1, qa2);
            ACC_EDGE(shB, wAb, wBb, qb0, qb1, qb2);
        }
        if (j < jhi) {
            const int sa = src_s[j];
            const float4 shA = sh_s[j];
            const _Float16* wra = w_s + (size_t)j * 128;
            const _Float16* yra = y + (size_t)sa * 128;
            const float wAa = (float)wra[wAi], wBa = (float)wra[wBi];
            const float qa0 = (float)yra[yi0], qa1 = (float)yra[yi1], qa2 = (float)yra[yi2];
            ACC_EDGE(shA, wAa, wBa, qa0, qa1, qa2);
        }

        const float rdeg = 1.0f / (float)deg;
        const float a = attr[n];

        float term = accA * rdeg * sWa[L];
#pragma unroll
        for (int off = 32; off; off >>= 1) term += __shfl_xor(term, off);
        const float alpha = term * 0.125f * a;

        midw[L]            = accA * rdeg;
        midw[64 + L]       = acc1 * rdeg;
        midw[128 + L]      = acc2 * rdeg;
        midw[192 + L]      = acc3 * rdeg;

        float cv1 = 0.f, cv2 = 0.f;
#pragma unroll
        for (int kk = 0; kk < 16; ++kk) {
            const float4 m1 = *(const float4*)&msrc1c[4 * kk];
            const float4 m2 = *(const float4*)&msrc2c[4 * kk];
            cv1 += m1.x * wcol1[(4 * kk + 0) * 32] + m1.y * wcol1[(4 * kk + 1) * 32]
                 + m1.z * wcol1[(4 * kk + 2) * 32] + m1.w * wcol1[(4 * kk + 3) * 32];
            cv2 += m2.x * wcol2[(4 * kk + 0) * 32] + m2.y * wcol2[(4 * kk + 1) * 32]
                 + m2.z * wcol2[(4 * kk + 2) * 32] + m2.w * wcol2[(4 * kk + 3) * 32];
        }
        const float f = alpha * 0.125f * a;
        const size_t ob = (size_t)n * 128;
        out[ob + L]      += f * cv1;
        out[ob + 64 + L] += f * cv2;
    }
#undef ACC_EDGE
}

extern "C" void kernel_launch(void* const* d_in, const int* in_sizes, int n_in,
                              void* d_out, int out_size, void* d_ws, size_t ws_size,
                              hipStream_t stream)
{
    const float* x      = (const float*)d_in[0];
    const float* attr   = (const float*)d_in[1];
    const int*   esrc   = (const int*)  d_in[2];
    const int*   edst   = (const int*)  d_in[3];
    const float* esh    = (const float*)d_in[4];
    const float* escal  = (const float*)d_in[5];
    const float* Wfc1   = (const float*)d_in[6];
    const float* Wfc2   = (const float*)d_in[7];
    const float* Wsc0   = (const float*)d_in[8];
    const float* Wsc1   = (const float*)d_in[9];
    const float* Wl10   = (const float*)d_in[10];
    const float* Wl11   = (const float*)d_in[11];
    const float* Wl20   = (const float*)d_in[12];
    const float* Wl21   = (const float*)d_in[13];
    const float* Walpha = (const float*)d_in[14];

    const int N = in_sizes[1];
    const int E = in_sizes[2];
    float* out = (float*)d_out;

    // ws: y(f16) | row_ptr | deg | cur | csr2edge | src_s | [align16] sh_s | w_s
    char* p = (char*)d_ws;
    _Float16* y   = (_Float16*)p; p += (size_t)N * 128 * sizeof(_Float16);
    int* row_ptr  = (int*)p;      p += (size_t)(N + 1) * sizeof(int);
    int* deg      = (int*)p;      p += (size_t)N * sizeof(int);
    int* cur      = (int*)p;      p += (size_t)N * sizeof(int);
    int* csr2edge = (int*)p;      p += (size_t)E * sizeof(int);
    int* src_s    = (int*)p;      p += (size_t)E * sizeof(int);
    p = (char*)(((uintptr_t)p + 15) & ~(uintptr_t)15);
    float4* sh_s  = (float4*)p;   p += (size_t)E * sizeof(float4);
    _Float16* w_s = (_Float16*)p;

    hipMemsetAsync(deg, 0, (size_t)2 * N * sizeof(int), stream);

    node_pre_kernel<<<1024, 256, 0, stream>>>(x, attr, Wsc0, Wsc1, Wl10, Wl11,
                                              out, y, N);
    hist_kernel<<<512, 256, 0, stream>>>(edst, deg, E);
    scan_kernel<<<1, 1024, 0, stream>>>(deg, row_ptr, N, E);
    fill_kernel<<<512, 256, 0, stream>>>(esrc, edst, esh, row_ptr, cur,
                                         csr2edge, src_s, sh_s, E);
    edge_w_kernel<<<1024, 256, 0, stream>>>(escal, csr2edge, Wfc1, Wfc2, w_s, E);
    gather_post_kernel<<<4096, 256, 0, stream>>>(w_s, src_s, sh_s, row_ptr,
                                                 y, attr, Wl20, Wl21, Walpha,
                                                 out, N);
}

// Round 17
// 243.224 us; speedup vs baseline: 1.7611x; 1.2901x over previous
//
#include <hip/hip_runtime.h>
#include <hip/hip_bf16.h>

#define MUL 32
#define SCAN_CH 1024

typedef _Float16 f16x8 __attribute__((ext_vector_type(8)));
typedef float f32x4 __attribute__((ext_vector_type(4)));

static __device__ __forceinline__ float silu_f(float z) {
    return z / (1.0f + __expf(-z));
}

// ---------------------------------------------------------------------------
// Kernel A: per-node pre-pass, wave-per-node, barrier-free. (r14/r15-verified)
// ---------------------------------------------------------------------------
__global__ __launch_bounds__(256) void node_pre_kernel(
    const float* __restrict__ x, const float* __restrict__ attr,
    const float* __restrict__ Wsc0, const float* __restrict__ Wsc1,
    const float* __restrict__ Wl10, const float* __restrict__ Wl11,
    float* __restrict__ sc_out, _Float16* __restrict__ y_out, int N)
{
    __shared__ float sX[4][128];
    const int tid = threadIdx.x;
    const int wid = tid >> 6, L = tid & 63;
    float* xs = sX[wid];
    const float inv = 0.17677669529663687f; // 1/sqrt(32)

    const bool t0 = (L < 32);
    const int i1 = t0 ? 0 : (L - 32);
    const int v1 = i1 / 3, c1 = i1 - v1 * 3;
    const int i2 = L + 32;
    const int v2 = i2 / 3, c2 = i2 - v2 * 3;

    const int xb1 = t0 ? 0 : (32 + c1);
    const int xst1 = t0 ? 1 : 3;

    float wA[32], wB[32], wC[32], wD[32];
#pragma unroll
    for (int u = 0; u < 32; ++u) {
        wA[u] = t0 ? Wsc0[u * 32 + L] : Wsc1[u * 32 + v1];
        wB[u] = t0 ? Wl10[u * 32 + L] : Wl11[u * 32 + v1];
        wC[u] = Wsc1[u * 32 + v2];
        wD[u] = Wl11[u * 32 + v2];
    }

    const int stride = gridDim.x * 4;
    for (int n = blockIdx.x * 4 + wid; n < N; n += stride) {
        xs[L]      = x[(size_t)n * 128 + L];
        xs[64 + L] = x[(size_t)n * 128 + 64 + L];
        const float scale = inv * attr[n];
        float a0 = 0.f, a1 = 0.f, b0 = 0.f, b1 = 0.f;
#pragma unroll
        for (int u = 0; u < 32; ++u) {
            const float xv1 = xs[xb1 + u * xst1];
            const float xv2 = xs[32 + u * 3 + c2];
            a0 += xv1 * wA[u];
            a1 += xv1 * wB[u];
            b0 += xv2 * wC[u];
            b1 += xv2 * wD[u];
        }
        sc_out[(size_t)n * 128 + L]      = a0 * scale;
        sc_out[(size_t)n * 128 + 64 + L] = b0 * scale;
        y_out [(size_t)n * 128 + L]      = (_Float16)(a1 * scale);
        y_out [(size_t)n * 128 + 64 + L] = (_Float16)(b1 * scale);
    }
}

// ---------------------------------------------------------------------------
// CSR build: histogram -> 3-phase coalesced scan -> fill.
// (r15's single-block scan replaced: it was 1 CU doing uncoalesced 200KB.)
// ---------------------------------------------------------------------------
__global__ void hist_kernel(const int* __restrict__ edst, int* __restrict__ deg, int E)
{
    int i = blockIdx.x * blockDim.x + threadIdx.x;
    const int stride = gridDim.x * blockDim.x;
    for (; i < E; i += stride) atomicAdd(&deg[edst[i]], 1);
}

__global__ __launch_bounds__(256) void scanA_kernel(
    const int* __restrict__ deg, int* __restrict__ bsum, int N)
{
    __shared__ int red[256];
    const int t = threadIdx.x, b = blockIdx.x;
    const int base = b * SCAN_CH;
    int s = 0;
#pragma unroll
    for (int k = 0; k < 4; ++k) {
        const int idx = base + t + k * 256;   // coalesced
        if (idx < N) s += deg[idx];
    }
    red[t] = s;
    __syncthreads();
    for (int off = 128; off; off >>= 1) {
        if (t < off) red[t] += red[t + off];
        __syncthreads();
    }
    if (t == 0) bsum[b] = red[0];
}

__global__ __launch_bounds__(256) void scanB_kernel(
    const int* __restrict__ bsum, int* __restrict__ boff, int NB)
{
    __shared__ int s[256];
    const int t = threadIdx.x;
    const int v = (t < NB) ? bsum[t] : 0;
    s[t] = v;
    __syncthreads();
    for (int off = 1; off < 256; off <<= 1) {
        const int add = (t >= off) ? s[t - off] : 0;
        __syncthreads();
        s[t] += add;
        __syncthreads();
    }
    if (t < NB) boff[t] = s[t] - v;   // exclusive
}

__global__ __launch_bounds__(256) void scanC_kernel(
    const int* __restrict__ deg, const int* __restrict__ boff,
    int* __restrict__ row_ptr, int N)
{
    __shared__ int ts[256];
    const int t = threadIdx.x, b = blockIdx.x;
    const int base = b * SCAN_CH + t * 4;
    int d0 = 0, d1 = 0, d2 = 0, d3 = 0;
    if (base + 0 < N) d0 = deg[base + 0];
    if (base + 1 < N) d1 = deg[base + 1];
    if (base + 2 < N) d2 = deg[base + 2];
    if (base + 3 < N) d3 = deg[base + 3];
    const int tsum = d0 + d1 + d2 + d3;
    ts[t] = tsum;
    __syncthreads();
    for (int off = 1; off < 256; off <<= 1) {
        const int add = (t >= off) ? ts[t - off] : 0;
        __syncthreads();
        ts[t] += add;
        __syncthreads();
    }
    int run = boff[b] + ts[t] - tsum;   // exclusive prefix at base
    if (base + 0 <= N) row_ptr[base + 0] = run;
    run += d0;
    if (base + 1 <= N) row_ptr[base + 1] = run;
    run += d1;
    if (base + 2 <= N) row_ptr[base + 2] = run;
    run += d2;
    if (base + 3 <= N) row_ptr[base + 3] = run;
}

__global__ void fill_kernel(
    const int* __restrict__ esrc, const int* __restrict__ edst,
    const float* __restrict__ esh,
    const int* __restrict__ row_ptr, int* __restrict__ cur,
    int* __restrict__ csr2edge, int* __restrict__ src_s, float4* __restrict__ sh_s,
    int E)
{
    int i = blockIdx.x * blockDim.x + threadIdx.x;
    const int stride = gridDim.x * blockDim.x;
    for (; i < E; i += stride) {
        const int d = edst[i];
        const int p = row_ptr[d] + atomicAdd(&cur[d], 1);
        csr2edge[p] = i;
        src_s[p] = esrc[i];
        sh_s[p] = *(const float4*)&esh[(size_t)i * 4];
    }
}

// ---------------------------------------------------------------------------
// Kernel B: edge MLP -> w (f16, CSR-slot order, sequential stores), 512-thread
// blocks: 8 waves share one 32KB W2T; LDS 64KB => exactly 2 blocks/CU, grid
// 512 => all blocks resident (zero tail), 16 waves/CU.
// ---------------------------------------------------------------------------
__global__ __launch_bounds__(512) void edge_w_kernel(
    const float* __restrict__ escal, const int* __restrict__ csr2edge,
    const float* __restrict__ Wfc1, const float* __restrict__ Wfc2,
    _Float16* __restrict__ w_s, int E)
{
    __shared__ _Float16 sW2T[128 * 128];   // 32 KB, [col][k] swizzled
    __shared__ _Float16 sH[8][16 * 128];   // 4 KB per wave (h, then w staging)

    const int tid = threadIdx.x;
    const int wid = tid >> 6;              // wave 0..7
    const int l   = tid & 63;
    const int c16 = l & 15;
    const int kq  = l >> 4;

    _Float16* Hw = sH[wid];

    {
        int* z2 = (int*)sW2T;
        for (int i = tid; i < 128 * 128 / 2; i += 512) z2[i] = 0;
    }
    __syncthreads();
    for (int i = tid; i < 100 * 128; i += 512) {
        const int k = i >> 7, col = i & 127;
        sW2T[col * 128 + (k ^ ((col & 7) << 3))] = (_Float16)Wfc2[i];
    }

    f16x8 bW1[7];
#pragma unroll
    for (int cb = 0; cb < 7; ++cb) {
        const int col = cb * 16 + c16;
#pragma unroll
        for (int j = 0; j < 8; ++j) {
            const int k = kq * 8 + j;
            bW1[cb][j] = (k < 10 && col < 100) ? (_Float16)Wfc1[k * 100 + col]
                                               : (_Float16)0.f;
        }
    }
#pragma unroll
    for (int r = 0; r < 4; ++r) {
        const int row = kq * 4 + r;
        const int col = 112 + c16;
        Hw[row * 128 + (col ^ ((row & 7) << 3))] = (_Float16)0.f;
    }
    __syncthreads();   // W2T visible to all waves; no barriers after this

    const float inv_s10 = 0.31622776601683794f; // 1/sqrt(10)

    const int gw = blockIdx.x * 8 + wid;
    const int nw = gridDim.x * 8;
    const int step = nw * 16;

    // prologue: csr2edge + gathered A1 for first iteration
    int base = gw * 16;
    f16x8 a1;
    {
        const int ge = base + c16;
        const int ee = (ge < E) ? csr2edge[ge] : 0;
#pragma unroll
        for (int j = 0; j < 8; ++j) {
            const int k = kq * 8 + j;
            a1[j] = (k < 10 && ge < E) ? (_Float16)escal[(size_t)ee * 10 + k]
                                       : (_Float16)0.f;
        }
    }

    for (; base < E; base += step) {
        // ---- phase 1: h = silu(escal@W1/sqrt10)*0.1 -> Hw (swizzled) ----
#pragma unroll
        for (int cb = 0; cb < 7; ++cb) {
            f32x4 z = {0.f, 0.f, 0.f, 0.f};
            z = __builtin_amdgcn_mfma_f32_16x16x32_f16(a1, bW1[cb], z, 0, 0, 0);
#pragma unroll
            for (int r = 0; r < 4; ++r) {
                const int row = kq * 4 + r;
                const int col = cb * 16 + c16;
                const float h = silu_f(z[r] * inv_s10) * 0.1f;
                Hw[row * 128 + (col ^ ((row & 7) << 3))] = (_Float16)h;
            }
        }

        // ---- prefetch next iteration's csr2edge + A1 (overlaps phase 2) ----
        f16x8 a1n;
        {
            const int ge = base + step + c16;
            const int ee = (ge < E) ? csr2edge[ge] : 0;
#pragma unroll
            for (int j = 0; j < 8; ++j) {
                const int k = kq * 8 + j;
                a1n[j] = (k < 10 && ge < E)
                         ? (_Float16)escal[(size_t)ee * 10 + k]
                         : (_Float16)0.f;
            }
        }

        // ---- phase 2: w = H @ W2 (A from Hw, B from sW2T; 32 MFMA) ----
        f32x4 acc0 = {0.f,0.f,0.f,0.f}, acc1 = {0.f,0.f,0.f,0.f};
        f32x4 acc2 = {0.f,0.f,0.f,0.f}, acc3 = {0.f,0.f,0.f,0.f};
        f32x4 acc4 = {0.f,0.f,0.f,0.f}, acc5 = {0.f,0.f,0.f,0.f};
        f32x4 acc6 = {0.f,0.f,0.f,0.f}, acc7 = {0.f,0.f,0.f,0.f};
#pragma unroll
        for (int kk = 0; kk < 4; ++kk) {
            const f16x8 a2 = *(const f16x8*)&Hw[c16 * 128 +
                                ((kk * 32 + kq * 8) ^ ((c16 & 7) << 3))];
#define BFRAG(CB) (*(const f16x8*)&sW2T[((CB) * 16 + c16) * 128 + \
                       ((kk * 32 + kq * 8) ^ ((c16 & 7) << 3))])
            acc0 = __builtin_amdgcn_mfma_f32_16x16x32_f16(a2, BFRAG(0), acc0, 0, 0, 0);
            acc1 = __builtin_amdgcn_mfma_f32_16x16x32_f16(a2, BFRAG(1), acc1, 0, 0, 0);
            acc2 = __builtin_amdgcn_mfma_f32_16x16x32_f16(a2, BFRAG(2), acc2, 0, 0, 0);
            acc3 = __builtin_amdgcn_mfma_f32_16x16x32_f16(a2, BFRAG(3), acc3, 0, 0, 0);
            acc4 = __builtin_amdgcn_mfma_f32_16x16x32_f16(a2, BFRAG(4), acc4, 0, 0, 0);
            acc5 = __builtin_amdgcn_mfma_f32_16x16x32_f16(a2, BFRAG(5), acc5, 0, 0, 0);
            acc6 = __builtin_amdgcn_mfma_f32_16x16x32_f16(a2, BFRAG(6), acc6, 0, 0, 0);
            acc7 = __builtin_amdgcn_mfma_f32_16x16x32_f16(a2, BFRAG(7), acc7, 0, 0, 0);
#undef BFRAG
        }

        // ---- stage w into Hw (h is dead now; per-wave in-order LDS) ----
#define STAGE_CB(CB, ACC)                                                     \
        {                                                                     \
            _Pragma("unroll")                                                 \
            for (int r = 0; r < 4; ++r) {                                     \
                const int row = kq * 4 + r;                                   \
                const int col = (CB) * 16 + c16;                              \
                Hw[row * 128 + (col ^ ((row & 7) << 3))] = (_Float16)(ACC)[r];\
            }                                                                 \
        }
        STAGE_CB(0, acc0) STAGE_CB(1, acc1) STAGE_CB(2, acc2) STAGE_CB(3, acc3)
        STAGE_CB(4, acc4) STAGE_CB(5, acc5) STAGE_CB(6, acc6) STAGE_CB(7, acc7)
#undef STAGE_CB

        // ---- 4x coalesced f16x8 stores per lane; CSR slots consecutive ----
#pragma unroll
        for (int i = 0; i < 4; ++i) {
            const int e = i * 4 + (l >> 4);
            const int colb = (l & 15) * 8;
            const f16x8 v = *(const f16x8*)&Hw[e * 128 +
                                (colb ^ ((e & 7) << 3))];
            if (base + e < E)
                *(f16x8*)&w_s[(size_t)(base + e) * 128 + colb] = v;
        }

        a1 = a1n;
    }
}

// ---------------------------------------------------------------------------
// Kernel C: gather + mean + fused post. Sequential w reads. (r15-verified)
// ---------------------------------------------------------------------------
__global__ __launch_bounds__(256) void gather_post_kernel(
    const _Float16* __restrict__ w_s, const int* __restrict__ src_s,
    const float4* __restrict__ sh_s, const int* __restrict__ row_ptr,
    const _Float16* __restrict__ y, const float* __restrict__ attr,
    const float* __restrict__ Wl20, const float* __restrict__ Wl21,
    const float* __restrict__ Walpha,
    float* __restrict__ out, int N)
{
    __shared__ float sW0[64 * 32];
    __shared__ float sW1[64 * 32];
    __shared__ float sWa[64];
    __shared__ float sMid[4][256];   // per-wave: [mid0(64) | midT(3x64)]

    const int tid = threadIdx.x;
    for (int i = tid; i < 64 * 32; i += 256) {
        sW0[i] = Wl20[i];
        sW1[i] = Wl21[i];
    }
    if (tid < 64) sWa[tid] = Walpha[tid];
    __syncthreads();   // only barrier; node loop is barrier-free

    const int wid = tid >> 6;
    const int L   = tid & 63;
    const bool hi = (L >= 32);
    const int u   = L & 31;

    const int wAi = hi ? 32 + u : u;
    const int wBi = hi ? 96 + u : 64 + u;
    const int yi0 = hi ? 32 + 3 * u + 0 : u;
    const int yi1 = hi ? 32 + 3 * u + 1 : u;
    const int yi2 = hi ? 32 + 3 * u + 2 : u;
    const float mulA = hi ? 0.5773502691896258f : 1.0f;   // 1/sqrt(3) on m11

    const int o1m = L - 32;
    const int v1 = hi ? o1m / 3 : 0;
    const int c1 = hi ? o1m - v1 * 3 : 0;
    const int o2m = L + 32;
    const int v2 = o2m / 3;
    const int c2 = o2m - v2 * 3;
    const float* wcol1 = hi ? (sW1 + v1) : (sW0 + L);
    const float* wcol2 = sW1 + v2;

    float* midw = &sMid[wid][0];
    const float* msrc1c = hi ? (midw + 64 + c1 * 64) : midw;
    const float* msrc2c = midw + 64 + c2 * 64;

#define ACC_EDGE(sh, wAv, wBv, q0, q1, q2) do {                        \
        const float sA0 = hi ? (sh).y : (sh).x;                        \
        const float sA1 = hi ? (sh).z : 0.f;                           \
        const float sA2 = hi ? (sh).w : 0.f;                           \
        const float b1s = hi ? (sh).x : (sh).y;                        \
        const float b2s = hi ? (sh).x : (sh).z;                        \
        const float b3s = hi ? (sh).x : (sh).w;                        \
        accA += (wAv) * mulA * ((q0) * sA0 + (q1) * sA1 + (q2) * sA2); \
        acc1 += (wBv) * (q0) * b1s;                                    \
        acc2 += (wBv) * (q1) * b2s;                                    \
        acc3 += (wBv) * (q2) * b3s;                                    \
    } while (0)

    const int waves_glob = gridDim.x * 4;
    for (int n = blockIdx.x * 4 + wid; n < N; n += waves_glob) {
        const int jlo = row_ptr[n];
        const int jhi = row_ptr[n + 1];
        const int deg = jhi - jlo;
        if (deg <= 0) continue;

        float accA = 0.f, acc1 = 0.f, acc2 = 0.f, acc3 = 0.f;

        int j = jlo;
        for (; j + 2 <= jhi; j += 2) {
            const int sa = src_s[j];
            const int sb = src_s[j + 1];
            const float4 shA = sh_s[j];
            const float4 shB = sh_s[j + 1];
            const _Float16* wra = w_s + (size_t)j * 128;
            const _Float16* wrb = wra + 128;
            const _Float16* yra = y + (size_t)sa * 128;
            const _Float16* yrb = y + (size_t)sb * 128;
            const float wAa = (float)wra[wAi], wBa = (float)wra[wBi];
            const float qa0 = (float)yra[yi0], qa1 = (float)yra[yi1], qa2 = (float)yra[yi2];
            const float wAb = (float)wrb[wAi], wBb = (float)wrb[wBi];
            const float qb0 = (float)yrb[yi0], qb1 = (float)yrb[yi1], qb2 = (float)yrb[yi2];
            ACC_EDGE(shA, wAa, wBa, qa0, qa1, qa2);
            ACC_EDGE(shB, wAb, wBb, qb0, qb1, qb2);
        }
        if (j < jhi) {
            const int sa = src_s[j];
            const float4 shA = sh_s[j];
            const _Float16* wra = w_s + (size_t)j * 128;
            const _Float16* yra = y + (size_t)sa * 128;
            const float wAa = (float)wra[wAi], wBa = (float)wra[wBi];
            const float qa0 = (float)yra[yi0], qa1 = (float)yra[yi1], qa2 = (float)yra[yi2];
            ACC_EDGE(shA, wAa, wBa, qa0, qa1, qa2);
        }

        const float rdeg = 1.0f / (float)deg;
        const float a = attr[n];

        float term = accA * rdeg * sWa[L];
#pragma unroll
        for (int off = 32; off; off >>= 1) term += __shfl_xor(term, off);
        const float alpha = term * 0.125f * a;

        midw[L]            = accA * rdeg;
        midw[64 + L]       = acc1 * rdeg;
        midw[128 + L]      = acc2 * rdeg;
        midw[192 + L]      = acc3 * rdeg;

        float cv1 = 0.f, cv2 = 0.f;
#pragma unroll
        for (int kk = 0; kk < 16; ++kk) {
            const float4 m1 = *(const float4*)&msrc1c[4 * kk];
            const float4 m2 = *(const float4*)&msrc2c[4 * kk];
            cv1 += m1.x * wcol1[(4 * kk + 0) * 32] + m1.y * wcol1[(4 * kk + 1) * 32]
                 + m1.z * wcol1[(4 * kk + 2) * 32] + m1.w * wcol1[(4 * kk + 3) * 32];
            cv2 += m2.x * wcol2[(4 * kk + 0) * 32] + m2.y * wcol2[(4 * kk + 1) * 32]
                 + m2.z * wcol2[(4 * kk + 2) * 32] + m2.w * wcol2[(4 * kk + 3) * 32];
        }
        const float f = alpha * 0.125f * a;
        const size_t ob = (size_t)n * 128;
        out[ob + L]      += f * cv1;
        out[ob + 64 + L] += f * cv2;
    }
#undef ACC_EDGE
}

extern "C" void kernel_launch(void* const* d_in, const int* in_sizes, int n_in,
                              void* d_out, int out_size, void* d_ws, size_t ws_size,
                              hipStream_t stream)
{
    const float* x      = (const float*)d_in[0];
    const float* attr   = (const float*)d_in[1];
    const int*   esrc   = (const int*)  d_in[2];
    const int*   edst   = (const int*)  d_in[3];
    const float* esh    = (const float*)d_in[4];
    const float* escal  = (const float*)d_in[5];
    const float* Wfc1   = (const float*)d_in[6];
    const float* Wfc2   = (const float*)d_in[7];
    const float* Wsc0   = (const float*)d_in[8];
    const float* Wsc1   = (const float*)d_in[9];
    const float* Wl10   = (const float*)d_in[10];
    const float* Wl11   = (const float*)d_in[11];
    const float* Wl20   = (const float*)d_in[12];
    const float* Wl21   = (const float*)d_in[13];
    const float* Walpha = (const float*)d_in[14];

    const int N = in_sizes[1];
    const int E = in_sizes[2];
    float* out = (float*)d_out;

    // ws: y(f16) | row_ptr | deg | cur | bsum | boff | csr2edge | src_s |
    //     [align16] sh_s | w_s
    char* p = (char*)d_ws;
    _Float16* y   = (_Float16*)p; p += (size_t)N * 128 * sizeof(_Float16);
    int* row_ptr  = (int*)p;      p += (size_t)(N + 1) * sizeof(int);
    int* deg      = (int*)p;      p += (size_t)N * sizeof(int);
    int* cur      = (int*)p;      p += (size_t)N * sizeof(int);
    int* bsum     = (int*)p;      p += 256 * sizeof(int);
    int* boff     = (int*)p;      p += 256 * sizeof(int);
    int* csr2edge = (int*)p;      p += (size_t)E * sizeof(int);
    int* src_s    = (int*)p;      p += (size_t)E * sizeof(int);
    p = (char*)(((uintptr_t)p + 15) & ~(uintptr_t)15);
    float4* sh_s  = (float4*)p;   p += (size_t)E * sizeof(float4);
    _Float16* w_s = (_Float16*)p;

    const int NB = (N + SCAN_CH) / SCAN_CH;   // covers row_ptr[N]

    hipMemsetAsync(deg, 0, (size_t)2 * N * sizeof(int), stream);

    node_pre_kernel<<<1024, 256, 0, stream>>>(x, attr, Wsc0, Wsc1, Wl10, Wl11,
                                              out, y, N);
    hist_kernel<<<512, 256, 0, stream>>>(edst, deg, E);
    scanA_kernel<<<NB, 256, 0, stream>>>(deg, bsum, N);
    scanB_kernel<<<1, 256, 0, stream>>>(bsum, boff, NB);
    scanC_kernel<<<NB, 256, 0, stream>>>(deg, boff, row_ptr, N);
    fill_kernel<<<512, 256, 0, stream>>>(esrc, edst, esh, row_ptr, cur,
                                         csr2edge, src_s, sh_s, E);
    edge_w_kernel<<<512, 512, 0, stream>>>(escal, csr2edge, Wfc1, Wfc2, w_s, E);
    gather_post_kernel<<<4096, 256, 0, stream>>>(w_s, src_s, sh_s, row_ptr,
                                                 y, attr, Wl20, Wl21, Walpha,
                                                 out, N);
}